// Round 10
// baseline (334.587 us; speedup 1.0000x reference)
//
#include <hip/hip_runtime.h>

typedef unsigned int uint32;
typedef unsigned short ushort16;

typedef __attribute__((ext_vector_type(8))) short short8;
typedef __attribute__((ext_vector_type(4))) float f32x4;

// ---------------------------------------------------------------------------
// GNN: h1 = relu((x + mean_agg(x)) @ W1 + b1)
//      h2 = relu((h1 + mean_agg(h1)) @ W2 + b2)
//      out = h2 @ Wp + bp
//
// R21: commuted pipeline + pure aggs + coarse prep.
//  R20 A/B result: pure agg = 63.5us @3.47TB/s (roofline); fused epilogue in
//  agg costs +13us (mechanism unclear, empirical). Budget: 127 agg + ~33
//  gemm + ~172 prep. Prep has cost 165-205us across 4 structures vs ~20us
//  BW floor — dominant target, but phases never appear in top-5.
//  This round:
//   * commute: y=x@W1 (f32 in) as filler in region-CSR kernel (R17-proven);
//     cvt pass eliminated.
//   * agg1 PURE (63.5); its bias+relu moved into gemm2's A-load (BW-bound,
//     VALU free). agg2 keeps R17 PROJ=1 path (76us proven).
//   * prep: count@CH=16K/1024t (98 blks) -> scan(196x98, tiny) ->
//     scatter@16K/1024t (98 blks, per-region ranges 84 edges=672B, full
//     lines). Coarse blocks: any slow phase now shows in top-5.
//  Pipeline: K1 count+Wt | K2 scan | K3 scatter | K4 csr(196)||gemm1(782)
//            | K5 agg1 | K6 gemm2(bias-relu A-load) | K7 agg2+proj.
// ---------------------------------------------------------------------------

#define RSH 9                  // 512 nodes per region
#define NRG 512                // nodes per region
#define CAP 12288              // rlist capacity per region (avg 8.2K, +45 sigma)
#define CH2 16384              // edges per count/scatter block

__device__ __forceinline__ ushort16 f2bf(float f) {
    uint32 u = __float_as_uint(f);
    u += 0x7fffu + ((u >> 16) & 1u);       // round-to-nearest-even
    return (ushort16)(u >> 16);
}
__device__ __forceinline__ float bfhi(uint32 u) { return __uint_as_float(u & 0xffff0000u); }
__device__ __forceinline__ float bflo(uint32 u) { return __uint_as_float(u << 16); }
__device__ __forceinline__ uint32 pack2(float a, float b) {
    return (uint32)f2bf(a) | ((uint32)f2bf(b) << 16);
}

union U16 { uint4 u; short8 s; };
__device__ __forceinline__ short8 ld_frag(const ushort16* p) {
    U16 x; x.u = *(const uint4*)p; return x.s;
}

#define ACC8(v) \
    acc[0] += bflo(v.x); acc[1] += bfhi(v.x); \
    acc[2] += bflo(v.y); acc[3] += bfhi(v.y); \
    acc[4] += bflo(v.z); acc[5] += bfhi(v.z); \
    acc[6] += bflo(v.w); acc[7] += bfhi(v.w);

// ---------------------------------------------------------------------------
// K1 (1024t): per-block region count + Wt prep on 2 extra blocks.
// ---------------------------------------------------------------------------
__global__ __launch_bounds__(1024)
void count_prep_kernel(const int* __restrict__ tgt, int* __restrict__ hist,
                       const float* __restrict__ W1, const float* __restrict__ W2,
                       ushort16* __restrict__ Wt1, ushort16* __restrict__ Wt2,
                       int E, int PB) {
    int tid = threadIdx.x, blk = blockIdx.x;
    if (blk >= PB) {   // Wt prep
        const float* W = (blk - PB) ? W2 : W1;
        ushort16* Wt = (blk - PB) ? Wt2 : Wt1;
        for (int i = tid; i < 16384; i += 1024) {
            int k = i >> 7, c = i & 127;
            Wt[c * 128 + k] = f2bf(W[i]);
        }
        return;
    }
    __shared__ int cnt[256];
    if (tid < 256) cnt[tid] = 0;
    __syncthreads();
    int q0 = blk * (CH2 / 4), q1 = min(q0 + CH2 / 4, E / 4);
    for (int q = q0 + tid; q < q1; q += 1024) {
        int4 t = ((const int4*)tgt)[q];
        atomicAdd(&cnt[t.x >> RSH], 1);
        atomicAdd(&cnt[t.y >> RSH], 1);
        atomicAdd(&cnt[t.z >> RSH], 1);
        atomicAdd(&cnt[t.w >> RSH], 1);
    }
    if (blk == 0 && tid == 0)
        for (int e = (E / 4) * 4; e < E; ++e) atomicAdd(&cnt[tgt[e] >> RSH], 1);
    __syncthreads();
    if (tid < 256) hist[(size_t)blk * 256 + tid] = cnt[tid];
}

// ---------------------------------------------------------------------------
// K2: per-region exclusive column scan of hist over PB blocks + total[r].
// PB <= 256 (single chunk).
// ---------------------------------------------------------------------------
__global__ __launch_bounds__(256)
void scan_kernel(int* __restrict__ hist, int* __restrict__ total, int PB) {
    __shared__ int sd[256];
    int r = blockIdx.x, tid = threadIdx.x;
    int v = (tid < PB) ? hist[(size_t)tid * 256 + r] : 0;
    sd[tid] = v;
    __syncthreads();
    for (int o = 1; o < 256; o <<= 1) {
        int t = (tid >= o) ? sd[tid - o] : 0;
        __syncthreads();
        sd[tid] += t;
        __syncthreads();
    }
    if (tid < PB) hist[(size_t)tid * 256 + r] = sd[tid] - v;
    if (tid == 255) total[r] = sd[255];
}

// ---------------------------------------------------------------------------
// K3 (1024t): scatter (src,tgt) into reserved per-block ranges of region lists.
// ---------------------------------------------------------------------------
__global__ __launch_bounds__(1024)
void scatter_kernel(const int* __restrict__ src, const int* __restrict__ tgt,
                    const int* __restrict__ hist, uint2* __restrict__ rlist,
                    int E) {
    __shared__ int cb[256];
    __shared__ int cnt[256];
    int tid = threadIdx.x, blk = blockIdx.x;
    if (tid < 256) {
        cnt[tid] = 0;
        cb[tid] = hist[(size_t)blk * 256 + tid];
    }
    __syncthreads();
    int q0 = blk * (CH2 / 4), q1 = min(q0 + CH2 / 4, E / 4);
    for (int q = q0 + tid; q < q1; q += 1024) {
        int4 t = ((const int4*)tgt)[q];
        int4 s = ((const int4*)src)[q];
        int r0 = t.x >> RSH, r1 = t.y >> RSH, r2 = t.z >> RSH, r3 = t.w >> RSH;
        int p0 = cb[r0] + atomicAdd(&cnt[r0], 1);
        int p1 = cb[r1] + atomicAdd(&cnt[r1], 1);
        int p2 = cb[r2] + atomicAdd(&cnt[r2], 1);
        int p3 = cb[r3] + atomicAdd(&cnt[r3], 1);
        if (p0 < CAP) rlist[(size_t)r0 * CAP + p0] = make_uint2((uint32)s.x, (uint32)t.x);
        if (p1 < CAP) rlist[(size_t)r1 * CAP + p1] = make_uint2((uint32)s.y, (uint32)t.y);
        if (p2 < CAP) rlist[(size_t)r2 * CAP + p2] = make_uint2((uint32)s.z, (uint32)t.z);
        if (p3 < CAP) rlist[(size_t)r3 * CAP + p3] = make_uint2((uint32)s.w, (uint32)t.w);
    }
    if (blk == 0 && tid == 0) {
        for (int e = (E / 4) * 4; e < E; ++e) {
            int t = tgt[e], r = t >> RSH;
            int p = cb[r] + atomicAdd(&cnt[r], 1);
            if (p < CAP) rlist[(size_t)r * CAP + p] = make_uint2((uint32)src[e], (uint32)t);
        }
    }
}

// ---------------------------------------------------------------------------
// GEMM per-wave body: 16 rows x 128 cols at row base r0w.
// MODE 0: A bf16.  MODE 1: A f32 (in-reg cvt).  MODE 2: A bf16 + relu(A+bias).
// ---------------------------------------------------------------------------
template<int MODE>
__device__ __forceinline__
void gemm_rows(const void* __restrict__ Asrc, const ushort16* __restrict__ Wt,
               const float* __restrict__ bias, int M,
               ushort16* __restrict__ outB, int r0w) {
    const int lane = threadIdx.x & 63;
    const int l15 = lane & 15;
    const int quad = lane >> 4;

    int arow = r0w + l15;
    if (arow >= M) arow = M - 1;

    short8 afr[4];
    if (MODE == 1) {
        const float* ap = (const float*)Asrc + (size_t)arow * 128 + quad * 8;
#pragma unroll
        for (int kt = 0; kt < 4; ++kt) {
            float4 a0 = *(const float4*)(ap + kt * 32);
            float4 a1 = *(const float4*)(ap + kt * 32 + 4);
            short8 f;
            f[0] = (short)f2bf(a0.x); f[1] = (short)f2bf(a0.y);
            f[2] = (short)f2bf(a0.z); f[3] = (short)f2bf(a0.w);
            f[4] = (short)f2bf(a1.x); f[5] = (short)f2bf(a1.y);
            f[6] = (short)f2bf(a1.z); f[7] = (short)f2bf(a1.w);
            afr[kt] = f;
        }
    } else if (MODE == 2) {
        const ushort16* aptr = (const ushort16*)Asrc + (size_t)arow * 128 + quad * 8;
#pragma unroll
        for (int kt = 0; kt < 4; ++kt) {
            uint4 v = *(const uint4*)(aptr + kt * 32);
            const float* bb = bias + kt * 32 + quad * 8;
            float4 b0 = *(const float4*)bb;
            float4 b1 = *(const float4*)(bb + 4);
            uint32 w0 = pack2(fmaxf(bflo(v.x) + b0.x, 0.f), fmaxf(bfhi(v.x) + b0.y, 0.f));
            uint32 w1 = pack2(fmaxf(bflo(v.y) + b0.z, 0.f), fmaxf(bfhi(v.y) + b0.w, 0.f));
            uint32 w2 = pack2(fmaxf(bflo(v.z) + b1.x, 0.f), fmaxf(bfhi(v.z) + b1.y, 0.f));
            uint32 w3 = pack2(fmaxf(bflo(v.w) + b1.z, 0.f), fmaxf(bfhi(v.w) + b1.w, 0.f));
            U16 u; u.u = make_uint4(w0, w1, w2, w3);
            afr[kt] = u.s;
        }
    } else {
        const ushort16* aptr = (const ushort16*)Asrc + (size_t)arow * 128 + quad * 8;
#pragma unroll
        for (int kt = 0; kt < 4; ++kt) afr[kt] = ld_frag(aptr + kt * 32);
    }

    f32x4 acc[8];
#pragma unroll
    for (int t = 0; t < 8; ++t) acc[t] = (f32x4){0.f, 0.f, 0.f, 0.f};

#pragma unroll
    for (int t = 0; t < 8; ++t) {
        const ushort16* bptr = Wt + (size_t)(16 * t + l15) * 128 + quad * 8;
        short8 b0 = ld_frag(bptr);
        short8 b1 = ld_frag(bptr + 32);
        short8 b2 = ld_frag(bptr + 64);
        short8 b3 = ld_frag(bptr + 96);
        acc[t] = __builtin_amdgcn_mfma_f32_16x16x32_bf16(afr[0], b0, acc[t], 0, 0, 0);
        acc[t] = __builtin_amdgcn_mfma_f32_16x16x32_bf16(afr[1], b1, acc[t], 0, 0, 0);
        acc[t] = __builtin_amdgcn_mfma_f32_16x16x32_bf16(afr[2], b2, acc[t], 0, 0, 0);
        acc[t] = __builtin_amdgcn_mfma_f32_16x16x32_bf16(afr[3], b3, acc[t], 0, 0, 0);
    }

#pragma unroll
    for (int t = 0; t < 8; ++t) {
        float ov[4];
        ov[0] = acc[t].x; ov[1] = acc[t].y; ov[2] = acc[t].z; ov[3] = acc[t].w;
#pragma unroll
        for (int r = 0; r < 4; ++r) {
            float nb = __shfl_xor(ov[r], 1, 64);
            int row = r0w + quad * 4 + r;
            if (((l15 & 1) == 0) && row < M) {
                *(uint32*)(outB + (size_t)row * 128 + 16 * t + l15) = pack2(ov[r], nb);
            }
        }
    }
}

// ---------------------------------------------------------------------------
// K4 (512t): blocks < R: per-region CSR build (8x-unrolled passes);
//            blocks >= R: GEMM1 (y = x @ W1, f32 in, 128 rows/block).
// ---------------------------------------------------------------------------
__global__ __launch_bounds__(512)
void csr_gemm1_kernel(const uint2* __restrict__ rlist, const int* __restrict__ total,
                      int* __restrict__ start, int* __restrict__ deg,
                      int* __restrict__ csr, int N, int R,
                      const float* __restrict__ x, const ushort16* __restrict__ Wt1,
                      ushort16* __restrict__ ybuf) {
    int blk = blockIdx.x;
    int tid = threadIdx.x;
    if (blk >= R) {
        int gid = blk - R;
        gemm_rows<1>(x, Wt1, nullptr, N, ybuf, gid * 128 + (tid >> 6) * 16);
        return;
    }
    __shared__ int lhist[NRG];
    __shared__ int sd[512];
    __shared__ int rbaseSh, countSh;

    int r = blk;
    // rbase = prefix of total over regions < r (256-wide scan; R <= 256)
    if (tid < 256) sd[tid] = (tid < R) ? total[tid] : 0;
    __syncthreads();
    for (int o = 1; o < 256; o <<= 1) {
        int t = (tid >= o && tid < 256) ? sd[tid - o] : 0;
        __syncthreads();
        if (tid < 256) sd[tid] += t;
        __syncthreads();
    }
    if (tid == 0) {
        rbaseSh = (r == 0) ? 0 : sd[r - 1];
        countSh = min(total[r], CAP);
    }
    if (tid < NRG) lhist[tid] = 0;
    __syncthreads();
    int count = countSh;
    const uint2* rl = rlist + (size_t)r * CAP;
    int n0 = r << RSH;

    // pass 1: degree histogram, 8x unrolled
    {
        int i = tid;
        for (; i + 512 * 7 < count; i += 512 * 8) {
            uint2 e0 = rl[i], e1 = rl[i + 512], e2 = rl[i + 1024], e3 = rl[i + 1536];
            uint2 e4 = rl[i + 2048], e5 = rl[i + 2560], e6 = rl[i + 3072], e7 = rl[i + 3584];
            atomicAdd(&lhist[e0.y & (NRG - 1)], 1);
            atomicAdd(&lhist[e1.y & (NRG - 1)], 1);
            atomicAdd(&lhist[e2.y & (NRG - 1)], 1);
            atomicAdd(&lhist[e3.y & (NRG - 1)], 1);
            atomicAdd(&lhist[e4.y & (NRG - 1)], 1);
            atomicAdd(&lhist[e5.y & (NRG - 1)], 1);
            atomicAdd(&lhist[e6.y & (NRG - 1)], 1);
            atomicAdd(&lhist[e7.y & (NRG - 1)], 1);
        }
        for (; i < count; i += 512)
            atomicAdd(&lhist[rl[i].y & (NRG - 1)], 1);
    }
    __syncthreads();

    // exclusive scan of 512; emit start/deg; lhist -> cursor
    {
        int v = lhist[tid];
        sd[tid] = v;
        __syncthreads();
        for (int o = 1; o < 512; o <<= 1) {
            int t = (tid >= o) ? sd[tid - o] : 0;
            __syncthreads();
            sd[tid] += t;
            __syncthreads();
        }
        int excl = sd[tid] - v + rbaseSh;
        int node = n0 + tid;
        if (node < N) { start[node] = excl; deg[node] = v; }
        lhist[tid] = excl;
        __syncthreads();
    }

    // pass 2: scatter into own csr window (~33KB, L2-local), 8x unrolled
    {
        int i = tid;
        for (; i + 512 * 7 < count; i += 512 * 8) {
            uint2 e0 = rl[i], e1 = rl[i + 512], e2 = rl[i + 1024], e3 = rl[i + 1536];
            uint2 e4 = rl[i + 2048], e5 = rl[i + 2560], e6 = rl[i + 3072], e7 = rl[i + 3584];
            int p0 = atomicAdd(&lhist[e0.y & (NRG - 1)], 1);
            int p1 = atomicAdd(&lhist[e1.y & (NRG - 1)], 1);
            int p2 = atomicAdd(&lhist[e2.y & (NRG - 1)], 1);
            int p3 = atomicAdd(&lhist[e3.y & (NRG - 1)], 1);
            int p4 = atomicAdd(&lhist[e4.y & (NRG - 1)], 1);
            int p5 = atomicAdd(&lhist[e5.y & (NRG - 1)], 1);
            int p6 = atomicAdd(&lhist[e6.y & (NRG - 1)], 1);
            int p7 = atomicAdd(&lhist[e7.y & (NRG - 1)], 1);
            csr[p0] = (int)e0.x; csr[p1] = (int)e1.x;
            csr[p2] = (int)e2.x; csr[p3] = (int)e3.x;
            csr[p4] = (int)e4.x; csr[p5] = (int)e5.x;
            csr[p6] = (int)e6.x; csr[p7] = (int)e7.x;
        }
        for (; i < count; i += 512) {
            uint2 e = rl[i];
            int p = atomicAdd(&lhist[e.y & (NRG - 1)], 1);
            csr[p] = (int)e.x;
        }
    }
}

// K6: z = relu(A + b1) @ W2   (bias-relu fused into A-load), 256t.
__global__ __launch_bounds__(256)
void gemm_biasrelu_kernel(const ushort16* __restrict__ A, const ushort16* __restrict__ Wt,
                          const float* __restrict__ bias, int M,
                          ushort16* __restrict__ outB) {
    gemm_rows<2>(A, Wt, bias, M, outB, blockIdx.x * 64 + ((threadIdx.x >> 6)) * 16);
}

// ---------------------------------------------------------------------------
// K5: pure agg (R20 verbatim, 63.5us): out = in_t + mean_{s in N(t)} in_s.
// ---------------------------------------------------------------------------
__global__ __launch_bounds__(256, 4)
void agg_combine_bf16_kernel(const ushort16* __restrict__ hb,
                             const int* __restrict__ startv, const int* __restrict__ degv,
                             const int* __restrict__ csr,
                             uint32* __restrict__ outb, int N) {
    int wid = (blockIdx.x * 256 + threadIdx.x) >> 6;
    int lane = threadIdx.x & 63;
    if (wid >= N) return;
    int g = lane >> 4, sl = lane & 15;
    int s0 = startv[wid];
    int deg = degv[wid];
    int fi = sl * 4 + g;
    uint32 su = ((const uint32*)hb)[(size_t)wid * 64 + fi];

    float acc[8];
#pragma unroll
    for (int j = 0; j < 8; ++j) acc[j] = 0.f;

    int base = 0;
    for (; base + 8 <= deg; base += 8) {
        int i0 = csr[s0 + base + g];
        int i1 = csr[s0 + base + 4 + g];
        uint4 v0 = *(const uint4*)(hb + (size_t)i0 * 128 + sl * 8);
        uint4 v1 = *(const uint4*)(hb + (size_t)i1 * 128 + sl * 8);
        ACC8(v0); ACC8(v1);
    }
    for (; base < deg; base += 4) {
        int e = base + g;
        if (e < deg) {
            int s = csr[s0 + e];
            uint4 v = *(const uint4*)(hb + (size_t)s * 128 + sl * 8);
            ACC8(v);
        }
    }
#pragma unroll
    for (int j = 0; j < 8; ++j) {
        acc[j] += __shfl_xor(acc[j], 16, 64);
        acc[j] += __shfl_xor(acc[j], 32, 64);
    }
    float inv = 1.f / fmaxf((float)deg, 1.f);
    float ax = (g == 0) ? acc[0] : (g == 1) ? acc[2] : (g == 2) ? acc[4] : acc[6];
    float ay = (g == 0) ? acc[1] : (g == 1) ? acc[3] : (g == 2) ? acc[5] : acc[7];
    outb[(size_t)wid * 64 + fi] = pack2(bflo(su) + ax * inv, bfhi(su) + ay * inv);
}

// ---------------------------------------------------------------------------
// K7 (R17 PROJ=1 verbatim): h = relu(in_t + mean + bias); out = h @ Wp + bp.
// ---------------------------------------------------------------------------
__global__ __launch_bounds__(256, 4)
void agg_proj_kernel(const ushort16* __restrict__ hb,
                     const int* __restrict__ startv, const int* __restrict__ degv,
                     const int* __restrict__ csr,
                     const float* __restrict__ bias,
                     const float* __restrict__ Wp, const float* __restrict__ bp,
                     float* __restrict__ outP, int N) {
    int wid = (blockIdx.x * 256 + threadIdx.x) >> 6;
    int lane = threadIdx.x & 63;
    if (wid >= N) return;
    int g = lane >> 4, sl = lane & 15;
    int s0 = startv[wid];
    int deg = degv[wid];
    int fi = sl * 4 + g;
    uint32 su = ((const uint32*)hb)[(size_t)wid * 64 + fi];

    float acc[8];
#pragma unroll
    for (int j = 0; j < 8; ++j) acc[j] = 0.f;

    int base = 0;
    for (; base + 8 <= deg; base += 8) {
        int i0 = csr[s0 + base + g];
        int i1 = csr[s0 + base + 4 + g];
        uint4 v0 = *(const uint4*)(hb + (size_t)i0 * 128 + sl * 8);
        uint4 v1 = *(const uint4*)(hb + (size_t)i1 * 128 + sl * 8);
        ACC8(v0); ACC8(v1);
    }
    for (; base < deg; base += 4) {
        int e = base + g;
        if (e < deg) {
            int s = csr[s0 + e];
            uint4 v = *(const uint4*)(hb + (size_t)s * 128 + sl * 8);
            ACC8(v);
        }
    }
#pragma unroll
    for (int j = 0; j < 8; ++j) {
        acc[j] += __shfl_xor(acc[j], 16, 64);
        acc[j] += __shfl_xor(acc[j], 32, 64);
    }
    float inv = 1.f / fmaxf((float)deg, 1.f);
    float ax = (g == 0) ? acc[0] : (g == 1) ? acc[2] : (g == 2) ? acc[4] : acc[6];
    float ay = (g == 0) ? acc[1] : (g == 1) ? acc[3] : (g == 2) ? acc[5] : acc[7];

    float ha = fmaxf(bflo(su) + ax * inv + bias[2 * fi],     0.f);
    float hc = fmaxf(bfhi(su) + ay * inv + bias[2 * fi + 1], 0.f);

    float p[5];
#pragma unroll
    for (int j = 0; j < 5; ++j)
        p[j] = ha * Wp[(2 * fi) * 5 + j] + hc * Wp[(2 * fi + 1) * 5 + j];
#pragma unroll
    for (int m = 1; m <= 32; m <<= 1)
#pragma unroll
        for (int j = 0; j < 5; ++j) p[j] += __shfl_xor(p[j], m, 64);
    if (lane == 0) {
#pragma unroll
        for (int j = 0; j < 5; ++j) outP[(size_t)wid * 5 + j] = p[j] + bp[j];
    }
}

extern "C" void kernel_launch(void* const* d_in, const int* in_sizes, int n_in,
                              void* d_out, int out_size, void* d_ws, size_t ws_size,
                              hipStream_t stream) {
    const float* x     = (const float*)d_in[0];
    const int*   edges = (const int*)d_in[1];
    const float* W1    = (const float*)d_in[2];
    const float* b1    = (const float*)d_in[3];
    const float* W2    = (const float*)d_in[4];
    const float* b2    = (const float*)d_in[5];
    const float* Wp    = (const float*)d_in[6];
    const float* bp    = (const float*)d_in[7];
    float* out = (float*)d_out;

    int N = in_sizes[0] / 128;   // 100000
    int E = in_sizes[1] / 2;     // 1600000
    const int* src = edges;
    const int* tgt = edges + E;

    const int R  = (N + NRG - 1) >> RSH;     // regions (196)
    const int PB = (E + CH2 - 1) / CH2;      // count/scatter blocks (98)

    char* ws = (char*)d_ws;
    size_t off = 0;
    auto alloc = [&](size_t bytes) {
        char* p = ws + off;
        off = (off + bytes + 255) & ~(size_t)255;
        return p;
    };
    int*      deg     = (int*)alloc((size_t)N * 4);
    int*      start   = (int*)alloc((size_t)N * 4);
    int*      csr     = (int*)alloc((size_t)E * 4);
    int*      hist    = (int*)alloc((size_t)PB * 256 * 4);
    int*      total   = (int*)alloc(256 * 4);
    uint2*    rlist   = (uint2*)alloc((size_t)R * CAP * 8);
    ushort16* ybuf    = (ushort16*)alloc((size_t)N * 128 * 2);  // y, later z
    ushort16* abuf    = (ushort16*)alloc((size_t)N * 128 * 2);  // a1
    ushort16* Wt1     = (ushort16*)alloc(128 * 128 * 2);
    ushort16* Wt2     = (ushort16*)alloc(128 * 128 * 2);
    (void)ws_size;

    const int g1Blocks   = (N + 127) / 128;      // 782 (512t blocks, 128 rows)
    const int gemmBlocks = (N + 63) / 64;        // 1563
    const int aggBlocks  = (N + 3) / 4;          // 25000

    // K1: region count (98 blocks) + Wt prep (2 blocks)
    count_prep_kernel<<<PB + 2, 1024, 0, stream>>>(tgt, hist, W1, W2, Wt1, Wt2, E, PB);
    // K2: per-region column scan -> per-block bases + total
    scan_kernel<<<R, 256, 0, stream>>>(hist, total, PB);
    // K3: scatter into per-region lists (reserved ranges, no global atomics)
    scatter_kernel<<<PB, 1024, 0, stream>>>(src, tgt, hist, rlist, E);
    // K4: per-region CSR build (196 blocks) || y = x @ W1 (782 blocks)
    csr_gemm1_kernel<<<R + g1Blocks, 512, 0, stream>>>(rlist, total, start, deg,
                                                       csr, N, R, x, Wt1, ybuf);
    // K5: a1 = y + mean_agg(y)   (pure, 63.5us)
    agg_combine_bf16_kernel<<<aggBlocks, 256, 0, stream>>>(ybuf, start, deg, csr,
                                                           (uint32*)abuf, N);
    // K6: z = relu(a1 + b1) @ W2  (bias-relu in A-load; reuse ybuf)
    gemm_biasrelu_kernel<<<gemmBlocks, 256, 0, stream>>>(abuf, Wt2, b1, N, ybuf);
    // K7: h2 = relu(z + mean_agg(z) + b2); out = h2 @ Wp + bp
    agg_proj_kernel<<<aggBlocks, 256, 0, stream>>>(ybuf, start, deg, csr, b2,
                                                   Wp, bp, out, N);
}

// Round 11
// 329.564 us; speedup vs baseline: 1.0152x; 1.0152x over previous
//
#include <hip/hip_runtime.h>

typedef unsigned int uint32;
typedef unsigned short ushort16;

typedef __attribute__((ext_vector_type(8))) short short8;
typedef __attribute__((ext_vector_type(4))) float f32x4;

// ---------------------------------------------------------------------------
// GNN: h1 = relu((x + mean_agg(x)) @ W1 + b1)
//      h2 = relu((h1 + mean_agg(h1)) @ W2 + b2)
//      out = h2 @ Wp + bp
//
// R22: recombine best-measured components.
//  Ledger (prep+gemms by subtraction): R11=235, R17=172.7(best), R20=205.5,
//  R21=195.2 — R17's geometry (NRG=2048, R=49, CH=2048@256t, csr+gemm1
//  @1024t) wins; restored VERBATIM. Aggs PURE (63.5us measured; fused
//  epilogues cost +12us per-wave serial work — confirmed twice, R20 & R21).
//  bias+relu in gemm2 A-load (MODE2, BW-bound => free, R21-verified).
//  Projection: thread-per-node kernel (640 FMA/thread, Wp/b2 in LDS uniform
//  broadcast, rows L1-resident) ~5us vs 12us wave-serial epilogue.
//  Pipeline: K1 count+Wt(782+16) | K2 scan(49) | K3 scatter(782) |
//            K4 csr(49)||gemm1(391)@1024t | K5 agg1 | K6 gemm2(biasrelu) |
//            K7 agg2 | K8 proj.
// ---------------------------------------------------------------------------

#define RSH 11                 // 2048 nodes per region
#define NRG 2048               // nodes per region
#define CAP 49152              // rlist capacity per region (avg 32.7K)
#define CH  2048               // edges per count/scatter block

__device__ __forceinline__ ushort16 f2bf(float f) {
    uint32 u = __float_as_uint(f);
    u += 0x7fffu + ((u >> 16) & 1u);       // round-to-nearest-even
    return (ushort16)(u >> 16);
}
__device__ __forceinline__ float bfhi(uint32 u) { return __uint_as_float(u & 0xffff0000u); }
__device__ __forceinline__ float bflo(uint32 u) { return __uint_as_float(u << 16); }
__device__ __forceinline__ uint32 pack2(float a, float b) {
    return (uint32)f2bf(a) | ((uint32)f2bf(b) << 16);
}

union U16 { uint4 u; short8 s; };
__device__ __forceinline__ short8 ld_frag(const ushort16* p) {
    U16 x; x.u = *(const uint4*)p; return x.s;
}

#define ACC8(v) \
    acc[0] += bflo(v.x); acc[1] += bfhi(v.x); \
    acc[2] += bflo(v.y); acc[3] += bfhi(v.y); \
    acc[4] += bflo(v.z); acc[5] += bfhi(v.z); \
    acc[6] += bflo(v.w); acc[7] += bfhi(v.w);

// ---------------------------------------------------------------------------
// K1: per-block region count (LDS only) + Wt prep on 16 extra blocks. [R17]
// ---------------------------------------------------------------------------
__global__ __launch_bounds__(256)
void count_prep_kernel(const int* __restrict__ tgt, int* __restrict__ hist,
                       const float* __restrict__ W1, const float* __restrict__ W2,
                       ushort16* __restrict__ Wt1, ushort16* __restrict__ Wt2,
                       int E, int PB, int R) {
    int tid = threadIdx.x, blk = blockIdx.x;
    if (blk >= PB) {   // Wt prep: 16 blocks, 2048 floats each, float4 loads
        int idx = blk - PB;
        const float* W = (idx >> 3) ? W2 : W1;
        ushort16* Wt = (idx >> 3) ? Wt2 : Wt1;
        int i0 = (idx & 7) * 2048 + tid * 8;
        float4 a = *(const float4*)(W + i0);
        float4 b = *(const float4*)(W + i0 + 4);
        int k = i0 >> 7, col = i0 & 127;
        Wt[(col + 0) * 128 + k] = f2bf(a.x);
        Wt[(col + 1) * 128 + k] = f2bf(a.y);
        Wt[(col + 2) * 128 + k] = f2bf(a.z);
        Wt[(col + 3) * 128 + k] = f2bf(a.w);
        Wt[(col + 4) * 128 + k] = f2bf(b.x);
        Wt[(col + 5) * 128 + k] = f2bf(b.y);
        Wt[(col + 6) * 128 + k] = f2bf(b.z);
        Wt[(col + 7) * 128 + k] = f2bf(b.w);
        return;
    }
    __shared__ int cnt[64];
    if (tid < 64) cnt[tid] = 0;
    __syncthreads();
    int q0 = blk * (CH / 4), q1 = min(q0 + CH / 4, E / 4);
    for (int q = q0 + tid; q < q1; q += 256) {
        int4 t = ((const int4*)tgt)[q];
        atomicAdd(&cnt[t.x >> RSH], 1);
        atomicAdd(&cnt[t.y >> RSH], 1);
        atomicAdd(&cnt[t.z >> RSH], 1);
        atomicAdd(&cnt[t.w >> RSH], 1);
    }
    if (blk == 0 && tid == 0)
        for (int e = (E / 4) * 4; e < E; ++e) atomicAdd(&cnt[tgt[e] >> RSH], 1);
    __syncthreads();
    if (tid < R) hist[(size_t)blk * 64 + tid] = cnt[tid];
}

// ---------------------------------------------------------------------------
// K2: per-region exclusive column scan of hist over PB blocks + total[r]. [R17]
// ---------------------------------------------------------------------------
__global__ __launch_bounds__(256)
void scan_kernel(int* __restrict__ hist, int* __restrict__ total, int PB) {
    __shared__ int sd[256];
    __shared__ int carrySh;
    int r = blockIdx.x, tid = threadIdx.x;
    if (tid == 0) carrySh = 0;
    __syncthreads();
    int chunks = (PB + 255) >> 8;
    for (int ch = 0; ch < chunks; ++ch) {
        int g = ch * 256 + tid;
        int v = (g < PB) ? hist[(size_t)g * 64 + r] : 0;
        int c0 = carrySh;
        sd[tid] = v;
        __syncthreads();
        for (int o = 1; o < 256; o <<= 1) {
            int t = (tid >= o) ? sd[tid - o] : 0;
            __syncthreads();
            sd[tid] += t;
            __syncthreads();
        }
        if (g < PB) hist[(size_t)g * 64 + r] = sd[tid] - v + c0;
        int tot = sd[255];
        __syncthreads();
        if (tid == 0) carrySh = c0 + tot;
        __syncthreads();
    }
    if (tid == 0) total[r] = carrySh;
}

// ---------------------------------------------------------------------------
// K3: scatter (src,tgt) into reserved per-block ranges of region lists. [R17]
// ---------------------------------------------------------------------------
__global__ __launch_bounds__(256)
void scatter_kernel(const int* __restrict__ src, const int* __restrict__ tgt,
                    const int* __restrict__ hist, uint2* __restrict__ rlist,
                    int E, int R) {
    __shared__ int cb[64];
    __shared__ int cnt[64];
    int tid = threadIdx.x, blk = blockIdx.x;
    if (tid < 64) {
        cnt[tid] = 0;
        cb[tid] = (tid < R) ? hist[(size_t)blk * 64 + tid] : 0;
    }
    __syncthreads();
    int q0 = blk * (CH / 4), q1 = min(q0 + CH / 4, E / 4);
    for (int q = q0 + tid; q < q1; q += 256) {
        int4 t = ((const int4*)tgt)[q];
        int4 s = ((const int4*)src)[q];
        int r0 = t.x >> RSH, r1 = t.y >> RSH, r2 = t.z >> RSH, r3 = t.w >> RSH;
        int p0 = cb[r0] + atomicAdd(&cnt[r0], 1);
        int p1 = cb[r1] + atomicAdd(&cnt[r1], 1);
        int p2 = cb[r2] + atomicAdd(&cnt[r2], 1);
        int p3 = cb[r3] + atomicAdd(&cnt[r3], 1);
        if (p0 < CAP) rlist[(size_t)r0 * CAP + p0] = make_uint2((uint32)s.x, (uint32)t.x);
        if (p1 < CAP) rlist[(size_t)r1 * CAP + p1] = make_uint2((uint32)s.y, (uint32)t.y);
        if (p2 < CAP) rlist[(size_t)r2 * CAP + p2] = make_uint2((uint32)s.z, (uint32)t.z);
        if (p3 < CAP) rlist[(size_t)r3 * CAP + p3] = make_uint2((uint32)s.w, (uint32)t.w);
    }
    if (blk == 0 && tid == 0) {
        for (int e = (E / 4) * 4; e < E; ++e) {
            int t = tgt[e], r = t >> RSH;
            int p = cb[r] + atomicAdd(&cnt[r], 1);
            if (p < CAP) rlist[(size_t)r * CAP + p] = make_uint2((uint32)src[e], (uint32)t);
        }
    }
}

// ---------------------------------------------------------------------------
// GEMM per-wave body: 16 rows x 128 cols at row base r0w.
// MODE 0: A bf16.  MODE 1: A f32 (in-reg cvt).  MODE 2: A bf16 + relu(A+bias).
// ---------------------------------------------------------------------------
template<int MODE>
__device__ __forceinline__
void gemm_rows(const void* __restrict__ Asrc, const ushort16* __restrict__ Wt,
               const float* __restrict__ bias, int M,
               ushort16* __restrict__ outB, int r0w) {
    const int lane = threadIdx.x & 63;
    const int l15 = lane & 15;
    const int quad = lane >> 4;

    int arow = r0w + l15;
    if (arow >= M) arow = M - 1;

    short8 afr[4];
    if (MODE == 1) {
        const float* ap = (const float*)Asrc + (size_t)arow * 128 + quad * 8;
#pragma unroll
        for (int kt = 0; kt < 4; ++kt) {
            float4 a0 = *(const float4*)(ap + kt * 32);
            float4 a1 = *(const float4*)(ap + kt * 32 + 4);
            short8 f;
            f[0] = (short)f2bf(a0.x); f[1] = (short)f2bf(a0.y);
            f[2] = (short)f2bf(a0.z); f[3] = (short)f2bf(a0.w);
            f[4] = (short)f2bf(a1.x); f[5] = (short)f2bf(a1.y);
            f[6] = (short)f2bf(a1.z); f[7] = (short)f2bf(a1.w);
            afr[kt] = f;
        }
    } else if (MODE == 2) {
        const ushort16* aptr = (const ushort16*)Asrc + (size_t)arow * 128 + quad * 8;
#pragma unroll
        for (int kt = 0; kt < 4; ++kt) {
            uint4 v = *(const uint4*)(aptr + kt * 32);
            const float* bb = bias + kt * 32 + quad * 8;
            float4 b0 = *(const float4*)bb;
            float4 b1 = *(const float4*)(bb + 4);
            uint32 w0 = pack2(fmaxf(bflo(v.x) + b0.x, 0.f), fmaxf(bfhi(v.x) + b0.y, 0.f));
            uint32 w1 = pack2(fmaxf(bflo(v.y) + b0.z, 0.f), fmaxf(bfhi(v.y) + b0.w, 0.f));
            uint32 w2 = pack2(fmaxf(bflo(v.z) + b1.x, 0.f), fmaxf(bfhi(v.z) + b1.y, 0.f));
            uint32 w3 = pack2(fmaxf(bflo(v.w) + b1.z, 0.f), fmaxf(bfhi(v.w) + b1.w, 0.f));
            U16 u; u.u = make_uint4(w0, w1, w2, w3);
            afr[kt] = u.s;
        }
    } else {
        const ushort16* aptr = (const ushort16*)Asrc + (size_t)arow * 128 + quad * 8;
#pragma unroll
        for (int kt = 0; kt < 4; ++kt) afr[kt] = ld_frag(aptr + kt * 32);
    }

    f32x4 acc[8];
#pragma unroll
    for (int t = 0; t < 8; ++t) acc[t] = (f32x4){0.f, 0.f, 0.f, 0.f};

#pragma unroll
    for (int t = 0; t < 8; ++t) {
        const ushort16* bptr = Wt + (size_t)(16 * t + l15) * 128 + quad * 8;
        short8 b0 = ld_frag(bptr);
        short8 b1 = ld_frag(bptr + 32);
        short8 b2 = ld_frag(bptr + 64);
        short8 b3 = ld_frag(bptr + 96);
        acc[t] = __builtin_amdgcn_mfma_f32_16x16x32_bf16(afr[0], b0, acc[t], 0, 0, 0);
        acc[t] = __builtin_amdgcn_mfma_f32_16x16x32_bf16(afr[1], b1, acc[t], 0, 0, 0);
        acc[t] = __builtin_amdgcn_mfma_f32_16x16x32_bf16(afr[2], b2, acc[t], 0, 0, 0);
        acc[t] = __builtin_amdgcn_mfma_f32_16x16x32_bf16(afr[3], b3, acc[t], 0, 0, 0);
    }

#pragma unroll
    for (int t = 0; t < 8; ++t) {
        float ov[4];
        ov[0] = acc[t].x; ov[1] = acc[t].y; ov[2] = acc[t].z; ov[3] = acc[t].w;
#pragma unroll
        for (int r = 0; r < 4; ++r) {
            float nb = __shfl_xor(ov[r], 1, 64);
            int row = r0w + quad * 4 + r;
            if (((l15 & 1) == 0) && row < M) {
                *(uint32*)(outB + (size_t)row * 128 + 16 * t + l15) = pack2(ov[r], nb);
            }
        }
    }
}

// ---------------------------------------------------------------------------
// K4 (1024t): blocks < R: per-region CSR build; blocks >= R: GEMM1 (f32 in).
// [R17 verbatim]
// ---------------------------------------------------------------------------
__global__ __launch_bounds__(1024)
void csr_gemm1_kernel(const uint2* __restrict__ rlist, const int* __restrict__ total,
                      int* __restrict__ start, int* __restrict__ deg,
                      int* __restrict__ csr, int N, int R,
                      const float* __restrict__ x, const ushort16* __restrict__ Wt1,
                      ushort16* __restrict__ ybuf) {
    int blk = blockIdx.x;
    int tid = threadIdx.x;
    if (blk >= R) {
        int gid = blk - R;
        gemm_rows<1>(x, Wt1, nullptr, N, ybuf, gid * 256 + (tid >> 6) * 16);
        return;
    }
    __shared__ int hist[NRG];
    __shared__ int sd[1024];
    __shared__ int carrySh;
    __shared__ int rbaseSh, countSh;

    int r = blk;
    if (tid == 0) countSh = min(total[r], CAP);
    if (tid < 64) {   // wave 0: rbase = sum of totals of earlier regions (R<=64)
        int v = (tid < R) ? total[tid] : 0;
        int pm = (tid < r) ? v : 0;
#pragma unroll
        for (int o = 1; o < 64; o <<= 1) pm += __shfl_xor(pm, o, 64);
        if (tid == 0) rbaseSh = pm;
    }
    for (int i = tid; i < NRG; i += 1024) hist[i] = 0;
    __syncthreads();
    int count = countSh;
    const uint2* rl = rlist + (size_t)r * CAP;
    int n0 = r << RSH;

    // pass 1: degree histogram, 4x unrolled
    {
        int i = tid;
        for (; i + 3072 < count; i += 4096) {
            uint2 a = rl[i], b = rl[i + 1024], c = rl[i + 2048], d = rl[i + 3072];
            atomicAdd(&hist[a.y & (NRG - 1)], 1);
            atomicAdd(&hist[b.y & (NRG - 1)], 1);
            atomicAdd(&hist[c.y & (NRG - 1)], 1);
            atomicAdd(&hist[d.y & (NRG - 1)], 1);
        }
        for (; i < count; i += 1024)
            atomicAdd(&hist[rl[i].y & (NRG - 1)], 1);
    }
    __syncthreads();

    // exclusive scan of 2048 in 2 chunks of 1024; emit start/deg; hist->cursor
    if (tid == 0) carrySh = rbaseSh;
    __syncthreads();
    for (int ch = 0; ch < 2; ++ch) {
        int idx = ch * 1024 + tid;
        int v = hist[idx];
        int c0 = carrySh;
        sd[tid] = v;
        __syncthreads();
        for (int o = 1; o < 1024; o <<= 1) {
            int t = (tid >= o) ? sd[tid - o] : 0;
            __syncthreads();
            sd[tid] += t;
            __syncthreads();
        }
        int excl = sd[tid] - v + c0;
        int tot = sd[1023];
        int node = n0 + idx;
        if (node < N) { start[node] = excl; deg[node] = v; }
        __syncthreads();
        hist[idx] = excl;   // becomes scatter cursor
        if (tid == 0) carrySh = c0 + tot;
        __syncthreads();
    }

    // pass 2: scatter into own csr window, 4x unrolled
    {
        int i = tid;
        for (; i + 3072 < count; i += 4096) {
            uint2 a = rl[i], b = rl[i + 1024], c = rl[i + 2048], d = rl[i + 3072];
            int pa = atomicAdd(&hist[a.y & (NRG - 1)], 1);
            int pb = atomicAdd(&hist[b.y & (NRG - 1)], 1);
            int pc = atomicAdd(&hist[c.y & (NRG - 1)], 1);
            int pd = atomicAdd(&hist[d.y & (NRG - 1)], 1);
            csr[pa] = (int)a.x;
            csr[pb] = (int)b.x;
            csr[pc] = (int)c.x;
            csr[pd] = (int)d.x;
        }
        for (; i < count; i += 1024) {
            uint2 e = rl[i];
            int p = atomicAdd(&hist[e.y & (NRG - 1)], 1);
            csr[p] = (int)e.x;
        }
    }
}

// K6: z = relu(A + b1) @ W2 (bias-relu fused into A-load), 256t. [R21]
__global__ __launch_bounds__(256)
void gemm_biasrelu_kernel(const ushort16* __restrict__ A, const ushort16* __restrict__ Wt,
                          const float* __restrict__ bias, int M,
                          ushort16* __restrict__ outB) {
    gemm_rows<2>(A, Wt, bias, M, outB, blockIdx.x * 64 + ((threadIdx.x >> 6)) * 16);
}

// ---------------------------------------------------------------------------
// K5/K7: pure agg (measured 63.5us): out = in_t + mean_{s in N(t)} in_s.
// ---------------------------------------------------------------------------
__global__ __launch_bounds__(256, 4)
void agg_combine_bf16_kernel(const ushort16* __restrict__ hb,
                             const int* __restrict__ startv, const int* __restrict__ degv,
                             const int* __restrict__ csr,
                             uint32* __restrict__ outb, int N) {
    int wid = (blockIdx.x * 256 + threadIdx.x) >> 6;
    int lane = threadIdx.x & 63;
    if (wid >= N) return;
    int g = lane >> 4, sl = lane & 15;
    int s0 = startv[wid];
    int deg = degv[wid];
    int fi = sl * 4 + g;
    uint32 su = ((const uint32*)hb)[(size_t)wid * 64 + fi];

    float acc[8];
#pragma unroll
    for (int j = 0; j < 8; ++j) acc[j] = 0.f;

    int base = 0;
    for (; base + 8 <= deg; base += 8) {
        int i0 = csr[s0 + base + g];
        int i1 = csr[s0 + base + 4 + g];
        uint4 v0 = *(const uint4*)(hb + (size_t)i0 * 128 + sl * 8);
        uint4 v1 = *(const uint4*)(hb + (size_t)i1 * 128 + sl * 8);
        ACC8(v0); ACC8(v1);
    }
    for (; base < deg; base += 4) {
        int e = base + g;
        if (e < deg) {
            int s = csr[s0 + e];
            uint4 v = *(const uint4*)(hb + (size_t)s * 128 + sl * 8);
            ACC8(v);
        }
    }
#pragma unroll
    for (int j = 0; j < 8; ++j) {
        acc[j] += __shfl_xor(acc[j], 16, 64);
        acc[j] += __shfl_xor(acc[j], 32, 64);
    }
    float inv = 1.f / fmaxf((float)deg, 1.f);
    float ax = (g == 0) ? acc[0] : (g == 1) ? acc[2] : (g == 2) ? acc[4] : acc[6];
    float ay = (g == 0) ? acc[1] : (g == 1) ? acc[3] : (g == 2) ? acc[5] : acc[7];
    outb[(size_t)wid * 64 + fi] = pack2(bflo(su) + ax * inv, bfhi(su) + ay * inv);
}

// ---------------------------------------------------------------------------
// K8: projection, thread-per-node: out[n] = relu(w[n]+b2) @ Wp + bp.
// Wp/b2 staged in LDS (uniform broadcast reads); rows L1-resident.
// ---------------------------------------------------------------------------
__global__ __launch_bounds__(256)
void proj_kernel(const ushort16* __restrict__ w, const float* __restrict__ b2,
                 const float* __restrict__ Wp, const float* __restrict__ bp,
                 float* __restrict__ out, int N) {
    __shared__ float wps[640];
    __shared__ float b2s[128];
    int tid = threadIdx.x;
    for (int i = tid; i < 640; i += 256) wps[i] = Wp[i];
    if (tid < 128) b2s[tid] = b2[tid];
    __syncthreads();
    int n = blockIdx.x * 256 + tid;
    if (n >= N) return;
    const uint4* row = (const uint4*)(w + (size_t)n * 128);
    float p0 = 0.f, p1 = 0.f, p2 = 0.f, p3 = 0.f, p4 = 0.f;
#pragma unroll
    for (int q = 0; q < 16; ++q) {
        uint4 v = row[q];
        int c = q * 8;
        uint32 ww[4] = {v.x, v.y, v.z, v.w};
#pragma unroll
        for (int k = 0; k < 4; ++k) {
            float hlo = fmaxf(bflo(ww[k]) + b2s[c + 2 * k],     0.f);
            float hhi = fmaxf(bfhi(ww[k]) + b2s[c + 2 * k + 1], 0.f);
            const float* wl = &wps[(c + 2 * k) * 5];
            p0 += hlo * wl[0] + hhi * wl[5];
            p1 += hlo * wl[1] + hhi * wl[6];
            p2 += hlo * wl[2] + hhi * wl[7];
            p3 += hlo * wl[3] + hhi * wl[8];
            p4 += hlo * wl[4] + hhi * wl[9];
        }
    }
    float* o = out + (size_t)n * 5;
    o[0] = p0 + bp[0];
    o[1] = p1 + bp[1];
    o[2] = p2 + bp[2];
    o[3] = p3 + bp[3];
    o[4] = p4 + bp[4];
}

extern "C" void kernel_launch(void* const* d_in, const int* in_sizes, int n_in,
                              void* d_out, int out_size, void* d_ws, size_t ws_size,
                              hipStream_t stream) {
    const float* x     = (const float*)d_in[0];
    const int*   edges = (const int*)d_in[1];
    const float* W1    = (const float*)d_in[2];
    const float* b1    = (const float*)d_in[3];
    const float* W2    = (const float*)d_in[4];
    const float* b2    = (const float*)d_in[5];
    const float* Wp    = (const float*)d_in[6];
    const float* bp    = (const float*)d_in[7];
    float* out = (float*)d_out;

    int N = in_sizes[0] / 128;   // 100000
    int E = in_sizes[1] / 2;     // 1600000
    const int* src = edges;
    const int* tgt = edges + E;

    const int R  = (N + NRG - 1) >> RSH;     // regions (49)
    const int PB = (E + CH - 1) / CH;        // count/scatter blocks (782)

    char* ws = (char*)d_ws;
    size_t off = 0;
    auto alloc = [&](size_t bytes) {
        char* p = ws + off;
        off = (off + bytes + 255) & ~(size_t)255;
        return p;
    };
    int*      deg     = (int*)alloc((size_t)N * 4);
    int*      start   = (int*)alloc((size_t)N * 4);
    int*      csr     = (int*)alloc((size_t)E * 4);
    int*      hist    = (int*)alloc((size_t)PB * 64 * 4);
    int*      total   = (int*)alloc(64 * 4);
    ushort16* ybuf    = (ushort16*)alloc((size_t)N * 128 * 2);  // y, later z
    ushort16* abuf    = (ushort16*)alloc((size_t)N * 128 * 2);  // a1, later w
    ushort16* Wt1     = (ushort16*)alloc(128 * 128 * 2);
    ushort16* Wt2     = (ushort16*)alloc(128 * 128 * 2);
    uint2*    rlist   = (uint2*)alloc((size_t)R * CAP * 8);     // 19.3 MB
    (void)ws_size;

    const int g1Blocks   = (N + 255) / 256;      // 391 (1024t blocks, 256 rows)
    const int gemmBlocks = (N + 63) / 64;        // 1563
    const int aggBlocks  = (N + 3) / 4;          // 25000
    const int projBlocks = (N + 255) / 256;      // 391

    // K1: region count (782 blocks) + Wt prep (16 blocks)
    count_prep_kernel<<<PB + 16, 256, 0, stream>>>(tgt, hist, W1, W2, Wt1, Wt2,
                                                   E, PB, R);
    // K2: per-region column scan -> per-block bases + total
    scan_kernel<<<R, 256, 0, stream>>>(hist, total, PB);
    // K3: scatter into per-region lists (reserved ranges, no global atomics)
    scatter_kernel<<<PB, 256, 0, stream>>>(src, tgt, hist, rlist, E, R);
    // K4: per-region CSR build (49 blocks) || y = x @ W1 (391 blocks)
    csr_gemm1_kernel<<<R + g1Blocks, 1024, 0, stream>>>(rlist, total, start, deg,
                                                        csr, N, R, x, Wt1, ybuf);
    // K5: a1 = y + mean_agg(y)   (pure)
    agg_combine_bf16_kernel<<<aggBlocks, 256, 0, stream>>>(ybuf, start, deg, csr,
                                                           (uint32*)abuf, N);
    // K6: z = relu(a1 + b1) @ W2  (bias-relu in A-load; reuse ybuf)
    gemm_biasrelu_kernel<<<gemmBlocks, 256, 0, stream>>>(abuf, Wt2, b1, N, ybuf);
    // K7: w = z + mean_agg(z)    (pure; reuse abuf)
    agg_combine_bf16_kernel<<<aggBlocks, 256, 0, stream>>>(ybuf, start, deg, csr,
                                                           (uint32*)abuf, N);
    // K8: out = relu(w + b2) @ Wp + bp
    proj_kernel<<<projBlocks, 256, 0, stream>>>(abuf, b2, Wp, bp, out, N);
}